// Round 7
// baseline (82.214 us; speedup 1.0000x reference)
//
#include <hip/hip_runtime.h>

// DRN layer, deg-4 Taylor/moment factorization — register-resident n-plane.
//
//  Pw/m0 = 1 + (-w)(n1 + (-w)(n2 + (-w)(n3 + (-w) n4))),  n_i = (m_i/i!)/m0
//  m_n(k,l) = sum_p C(2n,p)(-s_l)^(2n-p) mom_p[i,k],  mom_p = sum_m s_m^p P[i,k,m]
//  sum_k log2(m0) cancels in softmax. poly in [0.907,1.102]; product over 16 k
//  in 2^+-2.4, over 64 k in 2^+-9.3 -> fp32-safe, ONE log2 per j, no max-shift.
//
// grid = 256 (one block per i), block = 1024 = 16 waves = (jg 0..3, kg 0..3).
// Wave (jg,kg) owns j in [jg*16,+16), k in [kg*16,+16): n(k,l) lives in VGPRs
// (8 float4 at a time), w broadcast via v_readlane from 16 lane-indexed VGPRs.
// Main loop does ZERO LDS traffic (R6's limiter: 12.3k cyc/CU of ds_read_b128).
// Cross-kg combine via 64 KB lds_pr slab, multiplied in the epilogue.

#define NUP 64
#define NLOW 64
#define QUP 64
#define QLOW 64

__global__ __launch_bounds__(1024, 1)
void drn_kernel(const float* __restrict__ P,
                const float* __restrict__ weight,
                const float* __restrict__ bias_abs,
                const float* __restrict__ bias_q,
                const float* __restrict__ lambda_abs,
                const float* __restrict__ lambda_q,
                float* __restrict__ out)
{
    __shared__ float lds_mom[NLOW * 12];            // mom_0..mom_8 per k (3 KB)
    __shared__ float lds_pr[4 * NUP * QUP];         // partial products [kg][j][l] (64 KB)

    const int i    = blockIdx.x;
    const int tid  = threadIdx.x;
    const int lane = tid & 63;
    const int wv   = __builtin_amdgcn_readfirstlane(tid >> 6);   // 0..15
    const int jg   = wv >> 2;                                    // 0..3
    const int kg   = wv & 3;                                     // 0..3

    // ---------------- preload w[jg*16+jj, kg*16 + (lane&15)] ----------------
    float wreg[16];
#pragma unroll
    for (int jj = 0; jj < 16; ++jj)
        wreg[jj] = weight[(size_t)(jg * 16 + jj) * NLOW + kg * 16 + (lane & 15)];

    // ---------------- phase 1: raw moments mom_0..8 ----------------
    // k = wv*4 + (lane>>4); 16 lanes per k, 4 m per lane.
    {
        const int kk = lane >> 4;
        const int mc = lane & 15;
        const int k  = wv * 4 + kk;
        const float4 pa = *reinterpret_cast<const float4*>(
            P + ((size_t)i * NLOW + k) * QLOW + mc * 4);

        float t0 = 0.f, t1 = 0.f, t2 = 0.f, t3 = 0.f, t4 = 0.f,
              t5 = 0.f, t6 = 0.f, t7 = 0.f, t8 = 0.f;
        const float s0 = (float)(mc * 4) * 0.015625f;
#define ACCM(PV, S) { float f = (PV); const float s_ = (S); \
        t0 += f; f *= s_; t1 += f; f *= s_; t2 += f; f *= s_; t3 += f; f *= s_; \
        t4 += f; f *= s_; t5 += f; f *= s_; t6 += f; f *= s_; t7 += f; f *= s_; t8 += f; }
        ACCM(pa.x, s0);
        ACCM(pa.y, s0 + 0.015625f);
        ACCM(pa.z, s0 + 0.03125f);
        ACCM(pa.w, s0 + 0.046875f);
#undef ACCM
#define RED9(OFF) { t0 += __shfl_xor(t0, OFF, 64); t1 += __shfl_xor(t1, OFF, 64); \
        t2 += __shfl_xor(t2, OFF, 64); t3 += __shfl_xor(t3, OFF, 64); \
        t4 += __shfl_xor(t4, OFF, 64); t5 += __shfl_xor(t5, OFF, 64); \
        t6 += __shfl_xor(t6, OFF, 64); t7 += __shfl_xor(t7, OFF, 64); \
        t8 += __shfl_xor(t8, OFF, 64); }
        RED9(1) RED9(2) RED9(4) RED9(8)
#undef RED9
        if (mc == 0) {
            float* mp = &lds_mom[k * 12];
            *reinterpret_cast<float4*>(mp)     = make_float4(t0, t1, t2, t3);
            *reinterpret_cast<float4*>(mp + 4) = make_float4(t4, t5, t6, t7);
            mp[8] = t8;
        }
    }
    __syncthreads();

    // ---------------- per-lane binomial coefficients ----------------
    const float s1l = (float)lane * 0.015625f;
    const float z  = -s1l;
    const float z2 = z * z, z3 = z2 * z, z4 = z2 * z2;
    const float z5 = z4 * z, z6 = z4 * z2, z7 = z6 * z, z8 = z4 * z4;
    const float c10 = z2,                c11 = 2.f * z;
    const float c20 = 0.5f * z4,         c21 = 2.f * z3,           c22 = 3.f * z2,
                c23 = 2.f * z;
    const float c30 = z6 * (1.f / 6.f),  c31 = z5,                 c32 = 2.5f * z4,
                c33 = (10.f / 3.f) * z3, c34 = 2.5f * z2,          c35 = z;
    const float c40 = z8 * (1.f / 24.f), c41 = z7 * (1.f / 3.f),   c42 = (7.f / 6.f) * z6,
                c43 = (7.f / 3.f) * z5,  c44 = (35.f / 12.f) * z4, c45 = (7.f / 3.f) * z3,
                c46 = (7.f / 6.f) * z2,  c47 = z * (1.f / 3.f);

    // ---------------- phase 2 + main loop: n in registers, zero LDS ----------------
    float pr[16];
#pragma unroll
    for (int jj = 0; jj < 16; ++jj) pr[jj] = 1.0f;

#pragma unroll
    for (int kh = 0; kh < 2; ++kh) {
        float4 nk[8];
#pragma unroll
        for (int t = 0; t < 8; ++t) {
            const int k = kg * 16 + kh * 8 + t;
            const float4 q0 = *reinterpret_cast<const float4*>(&lds_mom[k * 12]);
            const float4 q1 = *reinterpret_cast<const float4*>(&lds_mom[k * 12 + 4]);
            const float  q8 = lds_mom[k * 12 + 8];

            const float inv = 1.0f / q0.x;     // 1/m0
            const float m1 = fmaf(c10, q0.x, fmaf(c11, q0.y, q0.z));
            const float m2 = fmaf(c20, q0.x, fmaf(c21, q0.y, fmaf(c22, q0.z,
                             fmaf(c23, q0.w, 0.5f * q1.x))));
            const float m3 = fmaf(c30, q0.x, fmaf(c31, q0.y, fmaf(c32, q0.z,
                             fmaf(c33, q0.w, fmaf(c34, q1.x, fmaf(c35, q1.y,
                             (1.f / 6.f) * q1.z))))));
            const float m4 = fmaf(c40, q0.x, fmaf(c41, q0.y, fmaf(c42, q0.z,
                             fmaf(c43, q0.w, fmaf(c44, q1.x, fmaf(c45, q1.y,
                             fmaf(c46, q1.z, fmaf(c47, q1.w, (1.f / 24.f) * q8))))))));
            nk[t] = make_float4(m1 * inv, m2 * inv, m3 * inv, m4 * inv);
        }
#pragma unroll
        for (int t = 0; t < 8; ++t) {
            const float4 n = nk[t];
#pragma unroll
            for (int jj = 0; jj < 16; ++jj) {
                const float w_ = __int_as_float(
                    __builtin_amdgcn_readlane(__float_as_int(wreg[jj]), kh * 8 + t));
                float s = fmaf(-w_, n.w, n.z);
                s = fmaf(-w_, s, n.y);
                s = fmaf(-w_, s, n.x);
                pr[jj] *= fmaf(-w_, s, 1.0f);
            }
        }
    }

    // ---------------- write partial products ----------------
#pragma unroll
    for (int jj = 0; jj < 16; ++jj)
        lds_pr[((kg * NUP) + (jg * 16 + jj)) * QUP + lane] = pr[jj];
    __syncthreads();

    // ---------------- epilogue: combine kg, exponent_B, base-2 softmax ----------------
    const float LOG2E = 1.4426950408889634f;
#pragma unroll
    for (int jj = 0; jj < 4; ++jj) {
        const int j = wv * 4 + jj;
        const float v0 = lds_pr[(0 * NUP + j) * QUP + lane];
        const float v1 = lds_pr[(1 * NUP + j) * QUP + lane];
        const float v2 = lds_pr[(2 * NUP + j) * QUP + lane];
        const float v3 = lds_pr[(3 * NUP + j) * QUP + lane];
        float y = __log2f((v0 * v1) * (v2 * v3));      // |y| <= ~9.3
        const float dq = s1l - lambda_q[j];
        y = fmaf(-bias_q[j] * LOG2E, dq * dq, y);
        y = fmaf(-bias_abs[j] * LOG2E, fabsf(s1l - lambda_abs[j]), y);
        const float e = exp2f(y);                      // fp32-safe without max-shift
        float s = e;
#pragma unroll
        for (int off = 32; off >= 1; off >>= 1)
            s += __shfl_xor(s, off, 64);
        out[((size_t)i * NUP + j) * QUP + lane] = e / s;
    }
}

extern "C" void kernel_launch(void* const* d_in, const int* in_sizes, int n_in,
                              void* d_out, int out_size, void* d_ws, size_t ws_size,
                              hipStream_t stream) {
    const float* P          = (const float*)d_in[0];
    const float* weight     = (const float*)d_in[1];
    const float* bias_abs   = (const float*)d_in[2];
    const float* bias_q     = (const float*)d_in[3];
    const float* lambda_abs = (const float*)d_in[4];
    const float* lambda_q   = (const float*)d_in[5];
    (void)in_sizes; (void)n_in; (void)out_size; (void)d_ws; (void)ws_size;

    drn_kernel<<<dim3(256), dim3(1024), 0, stream>>>(
        P, weight, bias_abs, bias_q, lambda_abs, lambda_q, (float*)d_out);
}

// Round 8
// 79.254 us; speedup vs baseline: 1.0373x; 1.0373x over previous
//
#include <hip/hip_runtime.h>

// DRN layer, deg-4 Taylor/moment factorization, m0-normalized LDS coefficient plane.
// (R4 structure — best measured — with unrolled k-loop and shift-free softmax.)
//
//  T = exp(-w*d2), |w*d2| <= 0.097 -> deg-4 Taylor (rel err 7e-8).
//  Pw/m0 = 1 + (-w)(n1 + (-w)(n2 + (-w)(n3 + (-w) n4))),  n_i = (m_i/i!)/m0
//  m_n(k,l) = sum_p C(2n,p)(-s_l)^(2n-p) mom_p[i,k],  mom_p = sum_m s_m^p P[i,k,m]
//  sum_k log2(m0) is (j,l)-independent -> cancels in softmax. poly in [0.907,1.102]
//  -> product over 64 k within 2^+-9.3: ONE log2 per j, exp2 safe with NO max-shift.
//
// grid = 512 (i = bid>>1, jh = bid&1) -> 2 blocks/CU (critical: barrier phases of
// one block overlap the main loop of the co-resident block; the R5-R7 regressions
// all had 1 block/CU). block = 512 = 8 waves; lane = l; wave owns 4 j.
// Weight rows are wave-uniform -> scalar loads; k-loop fully unrolled so the
// compiler pipelines s_loads across chunks. Main loop per (k,lane): exactly one
// contiguous conflict-free ds_read_b128.

#define NUP 64
#define NLOW 64
#define QUP 64
#define QLOW 64

__global__ __launch_bounds__(512, 4)
void drn_kernel(const float* __restrict__ P,
                const float* __restrict__ weight,
                const float* __restrict__ bias_abs,
                const float* __restrict__ bias_q,
                const float* __restrict__ lambda_abs,
                const float* __restrict__ lambda_q,
                float* __restrict__ out)
{
    __shared__ float  lds_mom[NLOW * 12];        // mom_0..mom_8 per k
    __shared__ float4 lds_n[NLOW * QUP];         // (n1,n2,n3,n4) per (k,l)  64 KB

    const int i    = blockIdx.x >> 1;
    const int jh   = blockIdx.x & 1;
    const int tid  = threadIdx.x;
    const int lane = tid & 63;
    const int wv   = __builtin_amdgcn_readfirstlane(tid >> 6);   // 0..7, uniform

    // ---------------- phase 1: raw moments mom_0..8 ----------------
    // lane = (kk, mc): k = wv*8+kk ; m in [mc*8, mc*8+8)
    {
        const int kk = lane >> 3;
        const int mc = lane & 7;
        const int k  = wv * 8 + kk;
        const float* Pr = P + ((size_t)i * NLOW + k) * QLOW + mc * 8;
        const float4 pa = *reinterpret_cast<const float4*>(Pr);
        const float4 pb = *reinterpret_cast<const float4*>(Pr + 4);

        float t0 = 0.f, t1 = 0.f, t2 = 0.f, t3 = 0.f, t4 = 0.f,
              t5 = 0.f, t6 = 0.f, t7 = 0.f, t8 = 0.f;
        const float s0 = (float)(mc * 8) * 0.015625f;
#define ACCM(PV, S) { float f = (PV); const float s_ = (S); \
        t0 += f; f *= s_; t1 += f; f *= s_; t2 += f; f *= s_; t3 += f; f *= s_; \
        t4 += f; f *= s_; t5 += f; f *= s_; t6 += f; f *= s_; t7 += f; f *= s_; t8 += f; }
        ACCM(pa.x, s0);
        ACCM(pa.y, s0 + 0.015625f);
        ACCM(pa.z, s0 + 0.03125f);
        ACCM(pa.w, s0 + 0.046875f);
        ACCM(pb.x, s0 + 0.0625f);
        ACCM(pb.y, s0 + 0.078125f);
        ACCM(pb.z, s0 + 0.09375f);
        ACCM(pb.w, s0 + 0.109375f);
#undef ACCM
#define RED9(OFF) { t0 += __shfl_xor(t0, OFF, 64); t1 += __shfl_xor(t1, OFF, 64); \
        t2 += __shfl_xor(t2, OFF, 64); t3 += __shfl_xor(t3, OFF, 64); \
        t4 += __shfl_xor(t4, OFF, 64); t5 += __shfl_xor(t5, OFF, 64); \
        t6 += __shfl_xor(t6, OFF, 64); t7 += __shfl_xor(t7, OFF, 64); \
        t8 += __shfl_xor(t8, OFF, 64); }
        RED9(1) RED9(2) RED9(4)
#undef RED9
        if (mc == 0) {
            float* mp = &lds_mom[k * 12];
            *reinterpret_cast<float4*>(mp)     = make_float4(t0, t1, t2, t3);
            *reinterpret_cast<float4*>(mp + 4) = make_float4(t4, t5, t6, t7);
            mp[8] = t8;
        }
    }
    __syncthreads();

    // ---------------- phase 2: combine -> normalized n_i(k,l) plane ----------------
    const float s1l = (float)lane * 0.015625f;
    {
        const float z  = -s1l;
        const float z2 = z * z, z3 = z2 * z, z4 = z2 * z2;
        const float z5 = z4 * z, z6 = z4 * z2, z7 = z6 * z, z8 = z4 * z4;
        const float c10 = z2,                c11 = 2.f * z;
        const float c20 = 0.5f * z4,         c21 = 2.f * z3,          c22 = 3.f * z2,
                    c23 = 2.f * z;
        const float c30 = z6 * (1.f / 6.f),  c31 = z5,                c32 = 2.5f * z4,
                    c33 = (10.f / 3.f) * z3, c34 = 2.5f * z2,         c35 = z;
        const float c40 = z8 * (1.f / 24.f), c41 = z7 * (1.f / 3.f),  c42 = (7.f / 6.f) * z6,
                    c43 = (7.f / 3.f) * z5,  c44 = (35.f / 12.f) * z4, c45 = (7.f / 3.f) * z3,
                    c46 = (7.f / 6.f) * z2,  c47 = z * (1.f / 3.f);

#pragma unroll
        for (int kk = 0; kk < 8; ++kk) {
            const int k = wv * 8 + kk;
            const float4 q0 = *reinterpret_cast<const float4*>(&lds_mom[k * 12]);
            const float4 q1 = *reinterpret_cast<const float4*>(&lds_mom[k * 12 + 4]);
            const float  q8 = lds_mom[k * 12 + 8];

            const float inv = 1.0f / q0.x;     // 1/m0
            const float m1 = fmaf(c10, q0.x, fmaf(c11, q0.y, q0.z));
            const float m2 = fmaf(c20, q0.x, fmaf(c21, q0.y, fmaf(c22, q0.z,
                             fmaf(c23, q0.w, 0.5f * q1.x))));
            const float m3 = fmaf(c30, q0.x, fmaf(c31, q0.y, fmaf(c32, q0.z,
                             fmaf(c33, q0.w, fmaf(c34, q1.x, fmaf(c35, q1.y,
                             (1.f / 6.f) * q1.z))))));
            const float m4 = fmaf(c40, q0.x, fmaf(c41, q0.y, fmaf(c42, q0.z,
                             fmaf(c43, q0.w, fmaf(c44, q1.x, fmaf(c45, q1.y,
                             fmaf(c46, q1.z, fmaf(c47, q1.w, (1.f / 24.f) * q8))))))));

            lds_n[k * QUP + lane] = make_float4(m1 * inv, m2 * inv, m3 * inv, m4 * inv);
        }
    }
    __syncthreads();

    // ---------------- main loop: 64 k (fully unrolled), this wave's 4 j's ----------------
    // w rows are wave-uniform -> scalar loads; full unroll lets the compiler
    // hoist/pipeline the s_loads instead of stalling every 8 k.
    const float* __restrict__ w0r = weight + (size_t)(jh * 32 + wv * 4 + 0) * NLOW;
    const float* __restrict__ w1r = weight + (size_t)(jh * 32 + wv * 4 + 1) * NLOW;
    const float* __restrict__ w2r = weight + (size_t)(jh * 32 + wv * 4 + 2) * NLOW;
    const float* __restrict__ w3r = weight + (size_t)(jh * 32 + wv * 4 + 3) * NLOW;

    float pr0 = 1.f, pr1 = 1.f, pr2 = 1.f, pr3 = 1.f;
#pragma unroll
    for (int k8 = 0; k8 < 8; ++k8) {
        float w0[8], w1[8], w2[8], w3[8];
#pragma unroll
        for (int kk = 0; kk < 8; ++kk) {
            w0[kk] = w0r[k8 * 8 + kk];
            w1[kk] = w1r[k8 * 8 + kk];
            w2[kk] = w2r[k8 * 8 + kk];
            w3[kk] = w3r[k8 * 8 + kk];
        }
#pragma unroll
        for (int kk = 0; kk < 8; ++kk) {
            const float4 n = lds_n[(k8 * 8 + kk) * QUP + lane];
#define STEPJ(W, PR) { const float w_ = (W); \
            float t = fmaf(-w_, n.w, n.z); \
            t = fmaf(-w_, t, n.y); t = fmaf(-w_, t, n.x); \
            PR *= fmaf(-w_, t, 1.0f); }
            STEPJ(w0[kk], pr0)
            STEPJ(w1[kk], pr1)
            STEPJ(w2[kk], pr2)
            STEPJ(w3[kk], pr3)
#undef STEPJ
        }
    }

    // ---------------- epilogue: exponent_B + base-2 softmax (no max-shift) ----------------
    const float LOG2E = 1.4426950408889634f;
    auto finish = [&](float prv, int jj) {
        const int j = jh * 32 + wv * 4 + jj;
        const float dq = s1l - lambda_q[j];
        float y = __log2f(prv);                     // |y| <= ~9.3
        y = fmaf(-bias_q[j] * LOG2E, dq * dq, y);
        y = fmaf(-bias_abs[j] * LOG2E, fabsf(s1l - lambda_abs[j]), y);
        const float e = exp2f(y);                   // fp32-safe without max-shift
        float s = e;
#pragma unroll
        for (int off = 32; off >= 1; off >>= 1)
            s += __shfl_xor(s, off, 64);
        out[((size_t)i * NUP + j) * QUP + lane] = e / s;
    };
    finish(pr0, 0);
    finish(pr1, 1);
    finish(pr2, 2);
    finish(pr3, 3);
}

extern "C" void kernel_launch(void* const* d_in, const int* in_sizes, int n_in,
                              void* d_out, int out_size, void* d_ws, size_t ws_size,
                              hipStream_t stream) {
    const float* P          = (const float*)d_in[0];
    const float* weight     = (const float*)d_in[1];
    const float* bias_abs   = (const float*)d_in[2];
    const float* bias_q     = (const float*)d_in[3];
    const float* lambda_abs = (const float*)d_in[4];
    const float* lambda_q   = (const float*)d_in[5];
    (void)in_sizes; (void)n_in; (void)out_size; (void)d_ws; (void)ws_size;

    drn_kernel<<<dim3(512), dim3(512), 0, stream>>>(
        P, weight, bias_abs, bias_q, lambda_abs, lambda_q, (float*)d_out);
}

// Round 9
// 74.817 us; speedup vs baseline: 1.0989x; 1.0593x over previous
//
#include <hip/hip_runtime.h>
#include <hip/hip_fp16.h>

// DRN layer — economized-cubic / moment factorization, 8-byte LDS n-plane.
//
//  x = w*d2, |x| <= h = 0.1*(63/64)^2 = 0.0969.
//  exp(-x) ~= a0 - x + a2*x^2 - x^3/6   (Chebyshev-economized Taylor-4:
//      x^4 ~= h^2 x^2 - h^4/8 on [-h,h]; a2 = 1/2 + h^2/24, a0 = 1 - h^4/192)
//  equioscillating err 4.6e-7 (NOT one-signed like raw deg-3 truncation).
//  Pw = a0*m0 * [1 + (-w)(N1 + (-w)(N2 + (-w)N3))],
//     N1 = M1/m0, N2 = a2*M2/m0, N3 = (1/6)*M3/m0,  M_n = sum_m d2^n P[i,k,m].
//  a0*m0 is (j,l)-independent -> cancels in softmax (a0 dropped entirely).
//  M_n from raw moments mom_0..mom_6 via binomial in z = -s_l.
//  poly in [0.905,1.10] -> product over 64 k within 2^+-9.3: ONE log2 per j,
//  exp2-softmax safe with NO max-shift.
//
// grid = 512 (i = bid>>1, jh = bid&1) -> 2 blocks/CU (measured-best R4 config:
// co-resident block overlaps the other's barrier phases). block = 512 = 8 waves;
// lane = l; wave owns 4 j. Main loop per (k,lane): ONE conflict-free ds_read_b64
// (8-byte entry: n1 fp32 + (n2,n3) fp16x2) — half of R4's b128 LDS traffic.

#define NUP 64
#define NLOW 64
#define QUP 64
#define QLOW 64

__global__ __launch_bounds__(512, 4)
void drn_kernel(const float* __restrict__ P,
                const float* __restrict__ weight,
                const float* __restrict__ bias_abs,
                const float* __restrict__ bias_q,
                const float* __restrict__ lambda_abs,
                const float* __restrict__ lambda_q,
                float* __restrict__ out)
{
    __shared__ float  lds_mom[NLOW * 8];         // mom_0..mom_6 per k (+pad)  2 KB
    __shared__ float2 lds_n[NLOW * QUP];         // (n1 | n2,n3 fp16) per (k,l) 32 KB

    const int i    = blockIdx.x >> 1;
    const int jh   = blockIdx.x & 1;
    const int tid  = threadIdx.x;
    const int lane = tid & 63;
    const int wv   = __builtin_amdgcn_readfirstlane(tid >> 6);   // 0..7, uniform

    // ---------------- phase 1: raw moments mom_0..6 ----------------
    // lane = (kk, mc): k = wv*8+kk ; m in [mc*8, mc*8+8)
    {
        const int kk = lane >> 3;
        const int mc = lane & 7;
        const int k  = wv * 8 + kk;
        const float* Pr = P + ((size_t)i * NLOW + k) * QLOW + mc * 8;
        const float4 pa = *reinterpret_cast<const float4*>(Pr);
        const float4 pb = *reinterpret_cast<const float4*>(Pr + 4);

        float t0 = 0.f, t1 = 0.f, t2 = 0.f, t3 = 0.f, t4 = 0.f, t5 = 0.f, t6 = 0.f;
        const float s0 = (float)(mc * 8) * 0.015625f;
#define ACCM(PV, S) { float f = (PV); const float s_ = (S); \
        t0 += f; f *= s_; t1 += f; f *= s_; t2 += f; f *= s_; t3 += f; \
        f *= s_; t4 += f; f *= s_; t5 += f; f *= s_; t6 += f; }
        ACCM(pa.x, s0);
        ACCM(pa.y, s0 + 0.015625f);
        ACCM(pa.z, s0 + 0.03125f);
        ACCM(pa.w, s0 + 0.046875f);
        ACCM(pb.x, s0 + 0.0625f);
        ACCM(pb.y, s0 + 0.078125f);
        ACCM(pb.z, s0 + 0.09375f);
        ACCM(pb.w, s0 + 0.109375f);
#undef ACCM
#define RED7(OFF) { t0 += __shfl_xor(t0, OFF, 64); t1 += __shfl_xor(t1, OFF, 64); \
        t2 += __shfl_xor(t2, OFF, 64); t3 += __shfl_xor(t3, OFF, 64); \
        t4 += __shfl_xor(t4, OFF, 64); t5 += __shfl_xor(t5, OFF, 64); \
        t6 += __shfl_xor(t6, OFF, 64); }
        RED7(1) RED7(2) RED7(4)
#undef RED7
        if (mc == 0) {
            float* mp = &lds_mom[k * 8];
            *reinterpret_cast<float4*>(mp)     = make_float4(t0, t1, t2, t3);
            *reinterpret_cast<float4*>(mp + 4) = make_float4(t4, t5, t6, 0.f);
        }
    }
    __syncthreads();

    // ---------------- phase 2: combine -> 8-byte n(k,l) plane ----------------
    const float s1l = (float)lane * 0.015625f;
    {
        const float A2 = 0.50039123f;            // 1/2 + h^2/24, h = 0.1*(63/64)^2
        const float C6 = 1.0f / 6.0f;
        const float z  = -s1l;
        const float z2 = z * z, z3 = z2 * z, z4 = z2 * z2, z5 = z4 * z, z6 = z4 * z2;
        // M1 coeffs on mom0..2 ; M2 on mom0..4 ; M3 on mom0..6
        const float b10 = z2,        b11 = 2.f * z;
        const float b20 = z4,        b21 = 4.f * z3, b22 = 6.f * z2, b23 = 4.f * z;
        const float b30 = z6,        b31 = 6.f * z5, b32 = 15.f * z4,
                    b33 = 20.f * z3, b34 = 15.f * z2, b35 = 6.f * z;

#pragma unroll
        for (int kk = 0; kk < 8; ++kk) {
            const int k = wv * 8 + kk;
            const float4 q0 = *reinterpret_cast<const float4*>(&lds_mom[k * 8]);
            const float4 q1 = *reinterpret_cast<const float4*>(&lds_mom[k * 8 + 4]);

            const float inv = 1.0f / q0.x;       // 1/m0
            const float M1 = fmaf(b10, q0.x, fmaf(b11, q0.y, q0.z));
            const float M2 = fmaf(b20, q0.x, fmaf(b21, q0.y, fmaf(b22, q0.z,
                             fmaf(b23, q0.w, q1.x))));
            const float M3 = fmaf(b30, q0.x, fmaf(b31, q0.y, fmaf(b32, q0.z,
                             fmaf(b33, q0.w, fmaf(b34, q1.x, fmaf(b35, q1.y, q1.z))))));

            const float n1 = M1 * inv;
            const float n2 = A2 * M2 * inv;
            const float n3 = C6 * M3 * inv;

            union { __half2 h; float f; } pk;
            pk.h = __floats2half2_rn(n2, n3);
            float2 e; e.x = n1; e.y = pk.f;
            lds_n[k * QUP + lane] = e;
        }
    }
    __syncthreads();

    // ---------------- main loop: 64 k (rolled by 8), this wave's 4 j's ----------------
    // Weight rows are wave-uniform -> scalar-friendly addressing (R4 form).
    const float* __restrict__ w0r = weight + (size_t)(jh * 32 + wv * 4 + 0) * NLOW;
    const float* __restrict__ w1r = weight + (size_t)(jh * 32 + wv * 4 + 1) * NLOW;
    const float* __restrict__ w2r = weight + (size_t)(jh * 32 + wv * 4 + 2) * NLOW;
    const float* __restrict__ w3r = weight + (size_t)(jh * 32 + wv * 4 + 3) * NLOW;

    float pr0 = 1.f, pr1 = 1.f, pr2 = 1.f, pr3 = 1.f;
    for (int k8 = 0; k8 < 8; ++k8) {
        float w0[8], w1[8], w2[8], w3[8];
#pragma unroll
        for (int kk = 0; kk < 8; ++kk) {
            w0[kk] = w0r[k8 * 8 + kk];
            w1[kk] = w1r[k8 * 8 + kk];
            w2[kk] = w2r[k8 * 8 + kk];
            w3[kk] = w3r[k8 * 8 + kk];
        }
#pragma unroll
        for (int kk = 0; kk < 8; ++kk) {
            const float2 v = lds_n[(k8 * 8 + kk) * QUP + lane];
            union { float f; __half2 h; } pk; pk.f = v.y;
            const float2 n23 = __half22float2(pk.h);   // (n2, n3)
#define STEPJ(W, PR) { const float w_ = (W); \
            float t = fmaf(-w_, n23.y, n23.x); \
            t = fmaf(-w_, t, v.x); \
            PR *= fmaf(-w_, t, 1.0f); }
            STEPJ(w0[kk], pr0)
            STEPJ(w1[kk], pr1)
            STEPJ(w2[kk], pr2)
            STEPJ(w3[kk], pr3)
#undef STEPJ
        }
    }

    // ---------------- epilogue: exponent_B + base-2 softmax (no max-shift) ----------------
    const float LOG2E = 1.4426950408889634f;
    auto finish = [&](float prv, int jj) {
        const int j = jh * 32 + wv * 4 + jj;
        const float dq = s1l - lambda_q[j];
        float y = __log2f(prv);                     // |y| <= ~9.3
        y = fmaf(-bias_q[j] * LOG2E, dq * dq, y);
        y = fmaf(-bias_abs[j] * LOG2E, fabsf(s1l - lambda_abs[j]), y);
        const float e = exp2f(y);                   // fp32-safe without max-shift
        float s = e;
#pragma unroll
        for (int off = 32; off >= 1; off >>= 1)
            s += __shfl_xor(s, off, 64);
        out[((size_t)i * NUP + j) * QUP + lane] = e / s;
    };
    finish(pr0, 0);
    finish(pr1, 1);
    finish(pr2, 2);
    finish(pr3, 3);
}

extern "C" void kernel_launch(void* const* d_in, const int* in_sizes, int n_in,
                              void* d_out, int out_size, void* d_ws, size_t ws_size,
                              hipStream_t stream) {
    const float* P          = (const float*)d_in[0];
    const float* weight     = (const float*)d_in[1];
    const float* bias_abs   = (const float*)d_in[2];
    const float* bias_q     = (const float*)d_in[3];
    const float* lambda_abs = (const float*)d_in[4];
    const float* lambda_q   = (const float*)d_in[5];
    (void)in_sizes; (void)n_in; (void)out_size; (void)d_ws; (void)ws_size;

    drn_kernel<<<dim3(512), dim3(512), 0, stream>>>(
        P, weight, bias_abs, bias_q, lambda_abs, lambda_q, (float*)d_out);
}